// Round 1
// baseline (1003.516 us; speedup 1.0000x reference)
//
#include <hip/hip_runtime.h>
#include <hip/hip_bf16.h>
#include <stdint.h>

#define NUM_CLASS 100000
#define CPAD      100096      // padded to multiple of 128
#define EMB       512
#define NROW      1024

#define BM 128
#define BN 128
#define BK 64
#define LROW 72               // ushorts per LDS row: 64 + 8 pad (kills pow2 bank stride)

typedef __bf16 bf16x8 __attribute__((ext_vector_type(8)));
typedef float  f32x4  __attribute__((ext_vector_type(4)));

// ---- ws layout (bytes) ----
// [0,256)            uint hard_cnt
// [256, +4096)       ftl  [1024] f32
// [4352, +4096)      ftl2 [1024] f32
// [8704, +1MB)       A bf16  (1024 x 512)
// [1057280, +102.5M) B bf16  (100096 x 512, rows >=100000 zeroed)
#define WS_FTL  256
#define WS_FTL2 4352
#define WS_A    8704
#define WS_B    1057280

__device__ inline unsigned short f2bf(float x) {
    uint32_t u = __builtin_bit_cast(uint32_t, x);
    uint32_t r = u + 0x7FFFu + ((u >> 16) & 1u);   // RNE, inputs are finite
    return (unsigned short)(r >> 16);
}
__device__ inline unsigned int pack2(float a, float b) {
    return (unsigned int)f2bf(a) | ((unsigned int)f2bf(b) << 16);
}

// ---- normalize logits rows -> bf16 A ----
__global__ __launch_bounds__(256) void prep_a(const float* __restrict__ logits,
                                              unsigned short* __restrict__ A) {
    int wave = threadIdx.x >> 6, lane = threadIdx.x & 63;
    int row = blockIdx.x * 4 + wave;                 // 256 blocks * 4 rows = 1024
    const float4* src = (const float4*)(logits + (size_t)row * EMB + lane * 8);
    float4 a = src[0], b = src[1];
    float ss = a.x*a.x + a.y*a.y + a.z*a.z + a.w*a.w
             + b.x*b.x + b.y*b.y + b.z*b.z + b.w*b.w;
    for (int off = 32; off; off >>= 1) ss += __shfl_xor(ss, off, 64);
    float rs = rsqrtf(ss + 1e-12f);
    uint4 o;
    o.x = pack2(a.x*rs, a.y*rs); o.y = pack2(a.z*rs, a.w*rs);
    o.z = pack2(b.x*rs, b.y*rs); o.w = pack2(b.z*rs, b.w*rs);
    *(uint4*)(A + (size_t)row * EMB + lane * 8) = o;
}

// ---- normalize weight rows -> bf16 B (padded rows zero) ----
__global__ __launch_bounds__(256) void prep_b(const float* __restrict__ w,
                                              unsigned short* __restrict__ B) {
    int wave = threadIdx.x >> 6, lane = threadIdx.x & 63;
    int row = blockIdx.x * 4 + wave;                 // 25024 blocks * 4 = 100096
    uint4 o = {0u, 0u, 0u, 0u};
    if (row < NUM_CLASS) {
        const float4* src = (const float4*)(w + (size_t)row * EMB + lane * 8);
        float4 a = src[0], b = src[1];
        float ss = a.x*a.x + a.y*a.y + a.z*a.z + a.w*a.w
                 + b.x*b.x + b.y*b.y + b.z*b.z + b.w*b.w;
        for (int off = 32; off; off >>= 1) ss += __shfl_xor(ss, off, 64);
        float rs = rsqrtf(ss + 1e-12f);
        o.x = pack2(a.x*rs, a.y*rs); o.y = pack2(a.z*rs, a.w*rs);
        o.z = pack2(b.x*rs, b.y*rs); o.w = pack2(b.z*rs, b.w*rs);
    }
    *(uint4*)(B + (size_t)row * EMB + lane * 8) = o;
}

// ---- per-row target cosine + margin thresholds (fp32), zero counter ----
__global__ __launch_bounds__(64) void prep_rows(const float* __restrict__ logits,
                                                const float* __restrict__ w,
                                                const int* __restrict__ labels,
                                                float* __restrict__ ftl,
                                                float* __restrict__ ftl2,
                                                unsigned int* __restrict__ cnt) {
    int row = blockIdx.x, lane = threadIdx.x;
    if (row == 0 && lane == 0) *cnt = 0u;
    int lab = labels[row];
    const float4* lp = (const float4*)(logits + (size_t)row * EMB + lane * 8);
    const float4* wp = (const float4*)(w + (size_t)lab * EMB + lane * 8);
    float4 l0 = lp[0], l1 = lp[1], w0 = wp[0], w1 = wp[1];
    float sl = l0.x*l0.x + l0.y*l0.y + l0.z*l0.z + l0.w*l0.w
             + l1.x*l1.x + l1.y*l1.y + l1.z*l1.z + l1.w*l1.w;
    float sw = w0.x*w0.x + w0.y*w0.y + w0.z*w0.z + w0.w*w0.w
             + w1.x*w1.x + w1.y*w1.y + w1.z*w1.z + w1.w*w1.w;
    float d  = l0.x*w0.x + l0.y*w0.y + l0.z*w0.z + l0.w*w0.w
             + l1.x*w1.x + l1.y*w1.y + l1.z*w1.z + l1.w*w1.w;
    for (int off = 32; off; off >>= 1) {
        sl += __shfl_xor(sl, off, 64);
        sw += __shfl_xor(sw, off, 64);
        d  += __shfl_xor(d,  off, 64);
    }
    if (lane == 0) {
        float tgt = d * rsqrtf(sl + 1e-12f) * rsqrtf(sw + 1e-12f);
        tgt = fminf(1.0f, fmaxf(-1.0f, tgt));
        const float cos_m  = 0.8775825618903728f;   // cos(0.5)
        const float sin_m  = 0.479425538604203f;    // sin(0.5)
        const float theta  = -0.8775825618903728f;  // cos(pi-0.5)
        const float sinmm  = 0.2397127693021015f;   // sin(pi-0.5)*0.5
        const float cos_m_ = 0.9800665778412416f;   // cos(0.2)
        const float sin_m_ = 0.19866933079506122f;  // sin(0.2)
        const float sinmm_ = -0.03973386615901225f; // sin(-0.2)*0.2
        float st   = sqrtf(fmaxf(0.0f, 1.0f - tgt * tgt));
        float ctm  = tgt * cos_m  - st * sin_m;
        float ctm_ = tgt * cos_m_ - st * sin_m_;
        ftl[row]  = (tgt > theta)    ? ctm  : (tgt - sinmm);
        ftl2[row] = (tgt <= cos_m_)  ? ctm_ : (tgt + sinmm_);
    }
}

// ---- bf16 MFMA GEMM: cos = A * B^T, write clipped cos, count hard mask ----
__global__ __launch_bounds__(256) void gemm_count(const unsigned short* __restrict__ A,
                                                  const unsigned short* __restrict__ B,
                                                  const float* __restrict__ ftl,
                                                  float* __restrict__ out,
                                                  unsigned int* __restrict__ cnt) {
    __shared__ __align__(16) unsigned short lA[BM * LROW];
    __shared__ __align__(16) unsigned short lB[BN * LROW];
    int tid = threadIdx.x;
    int wave = tid >> 6, lane = tid & 63;
    int wm = wave >> 1, wn = wave & 1;
    int quad = lane >> 4, l16 = lane & 15;
    int bn = blockIdx.x, bm = blockIdx.y;

    f32x4 acc[4][4] = {};

    int srow  = tid >> 3;   // 0..31 (row within 32-row round)
    int sslot = tid & 7;    // 16B chunk within row
    const size_t a_base = ((size_t)bm * BM + srow) * EMB + sslot * 8;
    const size_t b_base = ((size_t)bn * BN + srow) * EMB + sslot * 8;

    for (int kk = 0; kk < EMB / BK; ++kk) {
        __syncthreads();
        int k0 = kk * BK;
#pragma unroll
        for (int r = 0; r < 4; ++r) {
            uint4 va = *(const uint4*)(A + a_base + (size_t)r * 32 * EMB + k0);
            uint4 vb = *(const uint4*)(B + b_base + (size_t)r * 32 * EMB + k0);
            *(uint4*)&lA[(srow + r * 32) * LROW + sslot * 8] = va;
            *(uint4*)&lB[(srow + r * 32) * LROW + sslot * 8] = vb;
        }
        __syncthreads();
#pragma unroll
        for (int ks = 0; ks < 2; ++ks) {
            bf16x8 af[4], bfr[4];
#pragma unroll
            for (int i = 0; i < 4; ++i) {
                int ar = wm * 64 + i * 16 + l16;
                af[i]  = *(const bf16x8*)&lA[ar * LROW + ks * 32 + quad * 8];
                int br = wn * 64 + i * 16 + l16;
                bfr[i] = *(const bf16x8*)&lB[br * LROW + ks * 32 + quad * 8];
            }
#pragma unroll
            for (int i = 0; i < 4; ++i)
#pragma unroll
                for (int j = 0; j < 4; ++j)
                    acc[i][j] = __builtin_amdgcn_mfma_f32_16x16x32_bf16(af[i], bfr[j], acc[i][j], 0, 0, 0);
        }
    }

    int local = 0;
#pragma unroll
    for (int i = 0; i < 4; ++i) {
        int row0 = bm * BM + wm * 64 + i * 16 + quad * 4;
        float f0 = ftl[row0], f1 = ftl[row0 + 1], f2 = ftl[row0 + 2], f3 = ftl[row0 + 3];
#pragma unroll
        for (int j = 0; j < 4; ++j) {
            int col = bn * BN + wn * 64 + j * 16 + l16;
            bool cv = col < NUM_CLASS;
#pragma unroll
            for (int r = 0; r < 4; ++r) {
                float c = acc[i][j][r];
                c = fminf(1.0f, fmaxf(-1.0f, c));
                if (cv) {
                    float fr = (r == 0) ? f0 : (r == 1) ? f1 : (r == 2) ? f2 : f3;
                    local += (c > fr) ? 1 : 0;
                    out[(size_t)(row0 + r) * NUM_CLASS + col] = c;
                }
            }
        }
    }
    for (int off = 32; off; off >>= 1) local += __shfl_down(local, off, 64);
    if (lane == 0) atomicAdd(cnt, (unsigned int)local);
}

// ---- elementwise epilogue: masks, noise scale, diagonal set, *S ----
__global__ __launch_bounds__(256) void apply_k(float* __restrict__ out,
                                               const float* __restrict__ ftl,
                                               const float* __restrict__ ftl2,
                                               const int* __restrict__ labels,
                                               const unsigned int* __restrict__ cnt) {
    int row = blockIdx.y;
    int c4 = blockIdx.x * blockDim.x + threadIdx.x;
    if (c4 >= NUM_CLASS / 4) return;
    float h = (float)(*cnt);
    float msm = ((2900.0f - h) / 2900.0f) * 0.01f;
    float t = 1.0f - msm / 0.7f;
    float ns = t * t;
    float f = ftl[row], f2 = ftl2[row];
    int lab = labels[row];
    float4* p = (float4*)(out + (size_t)row * NUM_CLASS) + c4;
    float4 v = *p;
    float r[4] = {v.x, v.y, v.z, v.w};
    int col = c4 * 4;
#pragma unroll
    for (int q = 0; q < 4; ++q) {
        float c = r[q];
        float o = (c > f) ? c * 1.2f : c;     // hard margin: *(T+1)
        if (c > f2) o = fmaxf(c * ns, 1e-30f); // noise branch overrides
        if (col + q == lab) o = f;             // diagonal set
        r[q] = o * 64.0f;                      // *S
    }
    *p = make_float4(r[0], r[1], r[2], r[3]);
}

extern "C" void kernel_launch(void* const* d_in, const int* in_sizes, int n_in,
                              void* d_out, int out_size, void* d_ws, size_t ws_size,
                              hipStream_t stream) {
    const float* logits = (const float*)d_in[0];
    const int*   labels = (const int*)d_in[1];
    const float* weight = (const float*)d_in[2];
    char* ws = (char*)d_ws;
    unsigned int*  cnt  = (unsigned int*)ws;
    float*         ftl  = (float*)(ws + WS_FTL);
    float*         ftl2 = (float*)(ws + WS_FTL2);
    unsigned short* A   = (unsigned short*)(ws + WS_A);
    unsigned short* B   = (unsigned short*)(ws + WS_B);
    float* out = (float*)d_out;

    prep_a<<<NROW / 4, 256, 0, stream>>>(logits, A);
    prep_b<<<CPAD / 4, 256, 0, stream>>>(weight, B);
    prep_rows<<<NROW, 64, 0, stream>>>(logits, weight, labels, ftl, ftl2, cnt);
    gemm_count<<<dim3(CPAD / BN, NROW / BM), 256, 0, stream>>>(A, B, ftl, out, cnt);
    apply_k<<<dim3((NUM_CLASS / 4 + 255) / 256, NROW), 256, 0, stream>>>(out, ftl, ftl2, labels, cnt);
}

// Round 3
// 976.547 us; speedup vs baseline: 1.0276x; 1.0276x over previous
//
#include <hip/hip_runtime.h>
#include <hip/hip_bf16.h>
#include <stdint.h>

#define NUM_CLASS 100000
#define CPAD      100096      // padded to multiple of 128
#define EMB       512
#define NROW      1024

#define BM 128
#define BN 128
#define BK 64                 // ushorts of K per tile

typedef __bf16 bf16x8 __attribute__((ext_vector_type(8)));
typedef float  f32x4  __attribute__((ext_vector_type(4)));

// ---- ws layout (bytes) ----
#define WS_FTL  256
#define WS_FTL2 4352
#define WS_A    8704
#define WS_B    1057280

__device__ inline unsigned short f2bf(float x) {
    uint32_t u = __builtin_bit_cast(uint32_t, x);
    uint32_t r = u + 0x7FFFu + ((u >> 16) & 1u);   // RNE, inputs are finite
    return (unsigned short)(r >> 16);
}
__device__ inline unsigned int pack2(float a, float b) {
    return (unsigned int)f2bf(a) | ((unsigned int)f2bf(b) << 16);
}

// async global->LDS, 16 B per lane; LDS dst is wave-uniform base + lane*16
__device__ __forceinline__ void gld16(const unsigned short* g, unsigned short* l) {
    __builtin_amdgcn_global_load_lds(
        (const __attribute__((address_space(1))) unsigned int*)g,
        (__attribute__((address_space(3))) unsigned int*)l,
        16, 0, 0);
}

// ---- normalize logits rows -> bf16 A ----
__global__ __launch_bounds__(256) void prep_a(const float* __restrict__ logits,
                                              unsigned short* __restrict__ A) {
    int wave = threadIdx.x >> 6, lane = threadIdx.x & 63;
    int row = blockIdx.x * 4 + wave;
    const float4* src = (const float4*)(logits + (size_t)row * EMB + lane * 8);
    float4 a = src[0], b = src[1];
    float ss = a.x*a.x + a.y*a.y + a.z*a.z + a.w*a.w
             + b.x*b.x + b.y*b.y + b.z*b.z + b.w*b.w;
    for (int off = 32; off; off >>= 1) ss += __shfl_xor(ss, off, 64);
    float rs = rsqrtf(ss + 1e-12f);
    uint4 o;
    o.x = pack2(a.x*rs, a.y*rs); o.y = pack2(a.z*rs, a.w*rs);
    o.z = pack2(b.x*rs, b.y*rs); o.w = pack2(b.z*rs, b.w*rs);
    *(uint4*)(A + (size_t)row * EMB + lane * 8) = o;
}

// ---- normalize weight rows -> bf16 B (padded rows zero) ----
__global__ __launch_bounds__(256) void prep_b(const float* __restrict__ w,
                                              unsigned short* __restrict__ B) {
    int wave = threadIdx.x >> 6, lane = threadIdx.x & 63;
    int row = blockIdx.x * 4 + wave;
    uint4 o = {0u, 0u, 0u, 0u};
    if (row < NUM_CLASS) {
        const float4* src = (const float4*)(w + (size_t)row * EMB + lane * 8);
        float4 a = src[0], b = src[1];
        float ss = a.x*a.x + a.y*a.y + a.z*a.z + a.w*a.w
                 + b.x*b.x + b.y*b.y + b.z*b.z + b.w*b.w;
        for (int off = 32; off; off >>= 1) ss += __shfl_xor(ss, off, 64);
        float rs = rsqrtf(ss + 1e-12f);
        o.x = pack2(a.x*rs, a.y*rs); o.y = pack2(a.z*rs, a.w*rs);
        o.z = pack2(b.x*rs, b.y*rs); o.w = pack2(b.z*rs, b.w*rs);
    }
    *(uint4*)(B + (size_t)row * EMB + lane * 8) = o;
}

// ---- per-row target cosine + margin thresholds (fp32), zero counter ----
__global__ __launch_bounds__(64) void prep_rows(const float* __restrict__ logits,
                                                const float* __restrict__ w,
                                                const int* __restrict__ labels,
                                                float* __restrict__ ftl,
                                                float* __restrict__ ftl2,
                                                unsigned int* __restrict__ cnt) {
    int row = blockIdx.x, lane = threadIdx.x;
    if (row == 0 && lane == 0) *cnt = 0u;
    int lab = labels[row];
    const float4* lp = (const float4*)(logits + (size_t)row * EMB + lane * 8);
    const float4* wp = (const float4*)(w + (size_t)lab * EMB + lane * 8);
    float4 l0 = lp[0], l1 = lp[1], w0 = wp[0], w1 = wp[1];
    float sl = l0.x*l0.x + l0.y*l0.y + l0.z*l0.z + l0.w*l0.w
             + l1.x*l1.x + l1.y*l1.y + l1.z*l1.z + l1.w*l1.w;
    float sw = w0.x*w0.x + w0.y*w0.y + w0.z*w0.z + w0.w*w0.w
             + w1.x*w1.x + w1.y*w1.y + w1.z*w1.z + w1.w*w1.w;
    float d  = l0.x*w0.x + l0.y*w0.y + l0.z*w0.z + l0.w*w0.w
             + l1.x*w1.x + l1.y*w1.y + l1.z*w1.z + l1.w*w1.w;
    for (int off = 32; off; off >>= 1) {
        sl += __shfl_xor(sl, off, 64);
        sw += __shfl_xor(sw, off, 64);
        d  += __shfl_xor(d,  off, 64);
    }
    if (lane == 0) {
        float tgt = d * rsqrtf(sl + 1e-12f) * rsqrtf(sw + 1e-12f);
        tgt = fminf(1.0f, fmaxf(-1.0f, tgt));
        const float cos_m  = 0.8775825618903728f;
        const float sin_m  = 0.479425538604203f;
        const float theta  = -0.8775825618903728f;
        const float sinmm  = 0.2397127693021015f;
        const float cos_m_ = 0.9800665778412416f;
        const float sin_m_ = 0.19866933079506122f;
        const float sinmm_ = -0.03973386615901225f;
        float st   = sqrtf(fmaxf(0.0f, 1.0f - tgt * tgt));
        float ctm  = tgt * cos_m  - st * sin_m;
        float ctm_ = tgt * cos_m_ - st * sin_m_;
        ftl[row]  = (tgt > theta)    ? ctm  : (tgt - sinmm);
        ftl2[row] = (tgt <= cos_m_)  ? ctm_ : (tgt + sinmm_);
    }
}

// ---- bf16 MFMA GEMM (m97 structure): cos = A * B^T, write clipped cos, count ----
// grid: x = bm (8, fast) so row-tiles sharing a B-tile are co-resident; y = bn (782)
__global__ __launch_bounds__(256) void gemm_count(const unsigned short* __restrict__ A,
                                                  const unsigned short* __restrict__ B,
                                                  const float* __restrict__ ftl,
                                                  float* __restrict__ out,
                                                  unsigned int* __restrict__ cnt) {
    __shared__ __align__(16) unsigned short lA[BM * BK];   // 16 KB, unpadded lane-order
    __shared__ __align__(16) unsigned short lB[BN * BK];   // 16 KB
    int tid = threadIdx.x;
    int wave = tid >> 6, lane = tid & 63;
    int wm = wave >> 1, wn = wave & 1;
    int quad = lane >> 4, l16 = lane & 15;
    int bm = blockIdx.x, bn = blockIdx.y;

    f32x4 acc[4][4] = {};

    int srow  = tid >> 3;   // 0..31
    int sslot = tid & 7;    // 16B chunk within row
    const unsigned short* a_src = A + ((size_t)bm * BM + srow) * EMB + sslot * 8;
    const unsigned short* b_src = B + ((size_t)bn * BN + srow) * EMB + sslot * 8;
    unsigned short* a_dst = &lA[tid * 8];   // = srow*64 + sslot*8 : lane-contiguous
    unsigned short* b_dst = &lB[tid * 8];

#pragma unroll 1
    for (int kk = 0; kk < EMB / BK; ++kk) {
        int k0 = kk * BK;
#pragma unroll
        for (int r = 0; r < 4; ++r) {
            gld16(a_src + (size_t)r * 32 * EMB + k0, a_dst + r * 32 * BK);
            gld16(b_src + (size_t)r * 32 * EMB + k0, b_dst + r * 32 * BK);
        }
        __syncthreads();   // drains vmcnt: staged data visible
#pragma unroll
        for (int ks = 0; ks < 2; ++ks) {
            bf16x8 af[4], bfr[4];
#pragma unroll
            for (int i = 0; i < 4; ++i) {
                int ar = wm * 64 + i * 16 + l16;
                af[i]  = *(const bf16x8*)&lA[ar * BK + ks * 32 + quad * 8];
                int br = wn * 64 + i * 16 + l16;
                bfr[i] = *(const bf16x8*)&lB[br * BK + ks * 32 + quad * 8];
            }
#pragma unroll
            for (int i = 0; i < 4; ++i)
#pragma unroll
                for (int j = 0; j < 4; ++j)
                    acc[i][j] = __builtin_amdgcn_mfma_f32_16x16x32_bf16(af[i], bfr[j], acc[i][j], 0, 0, 0);
        }
        __syncthreads();   // all reads done before next overwrite
    }

    int local = 0;
#pragma unroll
    for (int i = 0; i < 4; ++i) {
        int row0 = bm * BM + wm * 64 + i * 16 + quad * 4;
        float f0 = ftl[row0], f1 = ftl[row0 + 1], f2 = ftl[row0 + 2], f3 = ftl[row0 + 3];
#pragma unroll
        for (int j = 0; j < 4; ++j) {
            int col = bn * BN + wn * 64 + j * 16 + l16;
            bool cv = col < NUM_CLASS;
#pragma unroll
            for (int r = 0; r < 4; ++r) {
                float c = acc[i][j][r];
                c = fminf(1.0f, fmaxf(-1.0f, c));
                if (cv) {
                    float fr = (r == 0) ? f0 : (r == 1) ? f1 : (r == 2) ? f2 : f3;
                    local += (c > fr) ? 1 : 0;
                    out[(size_t)(row0 + r) * NUM_CLASS + col] = c;
                }
            }
        }
    }
    for (int off = 32; off; off >>= 1) local += __shfl_down(local, off, 64);
    if (lane == 0) atomicAdd(cnt, (unsigned int)local);
}

// ---- elementwise epilogue: masks, noise scale, diagonal set, *S ----
// 1D grid, exact cover: 1024 rows * 25000 float4/row = 25.6e6 -> 100000 blocks * 256
__global__ __launch_bounds__(256) void apply_k(float* __restrict__ out,
                                               const float* __restrict__ ftl,
                                               const float* __restrict__ ftl2,
                                               const int* __restrict__ labels,
                                               const unsigned int* __restrict__ cnt) {
    int idx = blockIdx.x * 256 + threadIdx.x;          // 0 .. 25.6e6-1
    int row = idx / 25000;                             // magic-mul; 25000 float4 per row
    int c4  = idx - row * 25000;
    float h = (float)(*cnt);
    float msm = ((2900.0f - h) / 2900.0f) * 0.01f;
    float t = 1.0f - msm / 0.7f;
    float ns = t * t;
    float f = ftl[row], f2 = ftl2[row];
    int lab = labels[row];
    float4* p = (float4*)(out + (size_t)row * NUM_CLASS) + c4;
    float4 v = *p;
    float r[4] = {v.x, v.y, v.z, v.w};
    int col = c4 * 4;
#pragma unroll
    for (int q = 0; q < 4; ++q) {
        float c = r[q];
        float o = (c > f) ? c * 1.2f : c;      // hard margin: *(T+1)
        if (c > f2) o = fmaxf(c * ns, 1e-30f); // noise branch overrides
        if (col + q == lab) o = f;             // diagonal set
        r[q] = o * 64.0f;                      // *S
    }
    *p = make_float4(r[0], r[1], r[2], r[3]);
}

extern "C" void kernel_launch(void* const* d_in, const int* in_sizes, int n_in,
                              void* d_out, int out_size, void* d_ws, size_t ws_size,
                              hipStream_t stream) {
    const float* logits = (const float*)d_in[0];
    const int*   labels = (const int*)d_in[1];
    const float* weight = (const float*)d_in[2];
    char* ws = (char*)d_ws;
    unsigned int*  cnt  = (unsigned int*)ws;
    float*         ftl  = (float*)(ws + WS_FTL);
    float*         ftl2 = (float*)(ws + WS_FTL2);
    unsigned short* A   = (unsigned short*)(ws + WS_A);
    unsigned short* B   = (unsigned short*)(ws + WS_B);
    float* out = (float*)d_out;

    prep_a<<<NROW / 4, 256, 0, stream>>>(logits, A);
    prep_b<<<CPAD / 4, 256, 0, stream>>>(weight, B);
    prep_rows<<<NROW, 64, 0, stream>>>(logits, weight, labels, ftl, ftl2, cnt);
    gemm_count<<<dim3(NROW / BM, CPAD / BN), 256, 0, stream>>>(A, B, ftl, out, cnt);
    apply_k<<<100000, 256, 0, stream>>>(out, ftl, ftl2, labels, cnt);
}